// Round 11
// baseline (590.842 us; speedup 1.0000x reference)
//
#include <hip/hip_runtime.h>
#include <float.h>

// VQ-VAE quantizer: z [16,64,64,64] f32 (NCHW), embedding [1024,64] f32.
// d_out (f32): [loss(1) | z_q_out(4194304) | one_hot(67108864) | indices(65536)]
// train_indices match numpy fp32 argmin BIT-EXACTLY (absmax 0.0, r3/r7/r9).
// Scoring math (per-code serial-FMA chain, pairwise A, contract-off epilogue,
// ascending first-index ties) is FROZEN. This round:
//  (a) argmin: explicit unroll-4 over codes — 4 independent FMA chains to hide
//      the wave-uniform row-load latency (VALUBusy 52% -> target 75%+).
//      Per-code math/compare order unchanged -> still bit-exact.
//  (b) one-hot: fused zero+scatter, 1024 blocks x 64 contiguous rows (256 KB
//      slab per block), replaces fill_oh + combine (r9 residual ~200 us).

#define K_CODES 1024
#define DIM 64
#define NPTS 65536            // 16*64*64 points
#define RANGES 8
#define CPR 128               // codes per range
#define ZQ_OFF 1
#define OH_OFF (1 + 4194304)
#define IDX_OFF (1 + 4194304 + 67108864)

// numpy pairwise_sum of x[c]*x[c], n=64: classic 8-accumulator pattern.
__device__ __forceinline__ float np_sumsq64(const float* x) {
#pragma clang fp contract(off)
    float t[DIM];
#pragma unroll
    for (int c = 0; c < DIM; ++c) t[c] = x[c] * x[c];
    float r[8];
#pragma unroll
    for (int j = 0; j < 8; ++j) r[j] = t[j];
#pragma unroll
    for (int i = 8; i < DIM; i += 8)
#pragma unroll
        for (int j = 0; j < 8; ++j) r[j] += t[i + j];
    return ((r[0] + r[1]) + (r[2] + r[3])) + ((r[4] + r[5]) + (r[6] + r[7]));
}

__global__ __launch_bounds__(256) void bk_kernel(const float* __restrict__ emb,
                                                 float* __restrict__ bkf) {
    int k = blockIdx.x * 256 + threadIdx.x;
    if (k >= K_CODES) return;
    bkf[k] = np_sumsq64(emb + (size_t)k * DIM);
}

// Each block: 256 points x 128 codes (one k-range). Unroll 4: chains m0..m3
// are each the SAME serial-FMA sequence as before (bit-exact); compares stay
// in ascending k order.
__global__ __launch_bounds__(256) void argmin_partial(
    const float* __restrict__ z, const float* __restrict__ emb,
    const float* __restrict__ bkf,
    float* __restrict__ pscore, int* __restrict__ pidx) {
    int t = threadIdx.x;
    int ptblk = blockIdx.x & 255;
    int range = blockIdx.x >> 8;
    int kbase = range * CPR;

    int n = ptblk * 256 + t;
    int b = n >> 12, hw = n & 4095;
    const float* zb = z + ((size_t)b << 18) + hw;   // b*64*4096 + hw
    float zd[DIM];
#pragma unroll
    for (int c = 0; c < DIM; ++c) zd[c] = zb[(size_t)c << 12];

    float A = np_sumsq64(zd);

    float best = FLT_MAX;
    int bi = kbase;
    for (int k = 0; k < CPR; k += 4) {
        const float4* e0 = (const float4*)(emb + (size_t)(kbase + k + 0) * DIM);
        const float4* e1 = (const float4*)(emb + (size_t)(kbase + k + 1) * DIM);
        const float4* e2 = (const float4*)(emb + (size_t)(kbase + k + 2) * DIM);
        const float4* e3 = (const float4*)(emb + (size_t)(kbase + k + 3) * DIM);
        float m0 = 0.f, m1 = 0.f, m2 = 0.f, m3 = 0.f;
#pragma unroll
        for (int i = 0; i < 16; ++i) {
            float4 v0 = e0[i], v1 = e1[i], v2 = e2[i], v3 = e3[i];
            float za = zd[i * 4 + 0], zbv = zd[i * 4 + 1];
            float zc = zd[i * 4 + 2], zdv = zd[i * 4 + 3];
            m0 = __builtin_fmaf(za, v0.x, m0); m0 = __builtin_fmaf(zbv, v0.y, m0);
            m0 = __builtin_fmaf(zc, v0.z, m0); m0 = __builtin_fmaf(zdv, v0.w, m0);
            m1 = __builtin_fmaf(za, v1.x, m1); m1 = __builtin_fmaf(zbv, v1.y, m1);
            m1 = __builtin_fmaf(zc, v1.z, m1); m1 = __builtin_fmaf(zdv, v1.w, m1);
            m2 = __builtin_fmaf(za, v2.x, m2); m2 = __builtin_fmaf(zbv, v2.y, m2);
            m2 = __builtin_fmaf(zc, v2.z, m2); m2 = __builtin_fmaf(zdv, v2.w, m2);
            m3 = __builtin_fmaf(za, v3.x, m3); m3 = __builtin_fmaf(zbv, v3.y, m3);
            m3 = __builtin_fmaf(zc, v3.z, m3); m3 = __builtin_fmaf(zdv, v3.w, m3);
        }
        float d0, d1, d2, d3;
        {
#pragma clang fp contract(off)
            float t0 = A + bkf[kbase + k + 0]; d0 = t0 - 2.0f * m0;
            float t1 = A + bkf[kbase + k + 1]; d1 = t1 - 2.0f * m1;
            float t2 = A + bkf[kbase + k + 2]; d2 = t2 - 2.0f * m2;
            float t3 = A + bkf[kbase + k + 3]; d3 = t3 - 2.0f * m3;
        }
        if (d0 < best) { best = d0; bi = kbase + k + 0; }   // ascending order:
        if (d1 < best) { best = d1; bi = kbase + k + 1; }   // first index wins
        if (d2 < best) { best = d2; bi = kbase + k + 2; }
        if (d3 < best) { best = d3; bi = kbase + k + 3; }
    }
    pscore[range * NPTS + n] = best;
    pidx[range * NPTS + n] = bi;
}

// Fused: per block of 64 points -- 8-range combine (first-index ties), write
// fidx + float idx, zero-fill the block's contiguous 64-row one-hot slab
// (256 KB) with aligned float4, then scatter the 64 ones. No memset needed.
__global__ __launch_bounds__(256) void onehot_combine(
    const float* __restrict__ pscore, const int* __restrict__ pidx,
    int* __restrict__ fidx, float* __restrict__ out) {
    __shared__ int sbi[64];
    int t = threadIdx.x;
    int n0 = blockIdx.x * 64;

    if (t < 64) {
        int n = n0 + t;
        float best = pscore[n];
        int bi = pidx[n];
#pragma unroll
        for (int r = 1; r < RANGES; ++r) {
            float s = pscore[r * NPTS + n];
            if (s < best) { best = s; bi = pidx[r * NPTS + n]; }  // ascending
        }
        fidx[n] = bi;
        out[IDX_OFF + n] = (float)bi;
        sbi[t] = bi;
    }
    __syncthreads();

    // zero-fill: dwords [base, base+65536); base%4==1 -> head 3, 16383 quads, tail 1
    size_t base = (size_t)OH_OFF + (size_t)n0 * K_CODES;
    float4* qb = (float4*)(out + base + 3);
    const float4 z4 = make_float4(0.f, 0.f, 0.f, 0.f);
#pragma unroll
    for (int i = 0; i < 64; ++i) {
        int q = i * 256 + t;
        if (q < 16383) qb[q] = z4;
    }
    if (t == 0) {
        out[base] = 0.f; out[base + 1] = 0.f; out[base + 2] = 0.f;
        out[base + 65535] = 0.f;
    }
    __syncthreads();
    if (t < 64) out[base + (size_t)t * K_CODES + sbi[t]] = 1.0f;
}

// Grid-stride over aligned quads of the z_q output region; block-level partial
// loss reduction, one atomicAdd per block.
#define ZQ_QUADS 1048575      // (4194304 - 3 - 1) / 4
__global__ __launch_bounds__(256) void zq_loss_kernel(
    const float* __restrict__ z, const float* __restrict__ emb,
    const int* __restrict__ fidx, float* __restrict__ out) {
    int tid = blockIdx.x * 256 + threadIdx.x;
    int stride = gridDim.x * 256;
    float acc = 0.0f;
    for (int q = tid; q < ZQ_QUADS; q += stride) {
        int o = 3 + 4 * q;
        float4 r;
        float* rp = (float*)&r;
#pragma unroll
        for (int j = 0; j < 4; ++j) {
            int oj = o + j;
            int hw = oj & 4095;
            int c = (oj >> 12) & 63;
            int b = oj >> 18;
            int n = (b << 12) | hw;
            float zq = emb[(size_t)fidx[n] * DIM + c];
            float zp = z[oj];
            rp[j] = zp + (zq - zp);
            float d = zq - zp;
            acc = __builtin_fmaf(d, d, acc);
        }
        *(float4*)(out + ZQ_OFF + o) = r;
    }
    if (tid == 0) {
        int extras[4] = {0, 1, 2, 4194303};
#pragma unroll
        for (int e = 0; e < 4; ++e) {
            int oj = extras[e];
            int hw = oj & 4095;
            int c = (oj >> 12) & 63;
            int b = oj >> 18;
            int n = (b << 12) | hw;
            float zq = emb[(size_t)fidx[n] * DIM + c];
            float zp = z[oj];
            out[ZQ_OFF + oj] = zp + (zq - zp);
            float d = zq - zp;
            acc = __builtin_fmaf(d, d, acc);
        }
    }
#pragma unroll
    for (int off = 32; off; off >>= 1) acc += __shfl_down(acc, off, 64);
    __shared__ float wsum[4];
    if ((threadIdx.x & 63) == 0) wsum[threadIdx.x >> 6] = acc;
    __syncthreads();
    if (threadIdx.x == 0) {
        float s = (wsum[0] + wsum[1]) + (wsum[2] + wsum[3]);
        // loss = (1 + beta) * mean((z_q - z)^2), beta = 0.25, N = 4194304
        atomicAdd(out, s * (1.25f / 4194304.0f));
    }
}

extern "C" void kernel_launch(void* const* d_in, const int* in_sizes, int n_in,
                              void* d_out, int out_size, void* d_ws, size_t ws_size,
                              hipStream_t stream) {
    const float* z = (const float*)d_in[0];
    const float* emb = (const float*)d_in[1];
    float* out = (float*)d_out;
    char* ws = (char*)d_ws;
    float* bkf = (float*)ws;                                     // 4 KB
    float* pscore = (float*)(ws + 8192);                         // 2 MB
    int* pidx = (int*)(ws + 8192 + (size_t)RANGES * NPTS * 4);   // 2 MB
    int* fidx = (int*)(ws + 8192 + (size_t)RANGES * NPTS * 8);   // 256 KB

    hipMemsetAsync(d_out, 0, 4, stream);   // loss accumulator
    hipLaunchKernelGGL(bk_kernel, dim3(4), dim3(256), 0, stream, emb, bkf);
    hipLaunchKernelGGL(argmin_partial, dim3(256 * RANGES), dim3(256), 0, stream,
                       z, emb, bkf, pscore, pidx);
    hipLaunchKernelGGL(onehot_combine, dim3(NPTS / 64), dim3(256), 0, stream,
                       pscore, pidx, fidx, out);
    hipLaunchKernelGGL(zq_loss_kernel, dim3(1024), dim3(256), 0, stream,
                       z, emb, fidx, out);
}

// Round 15
// 506.379 us; speedup vs baseline: 1.1668x; 1.1668x over previous
//
#include <hip/hip_runtime.h>
#include <float.h>

// VQ-VAE quantizer: z [16,64,64,64] f32 (NCHW), embedding [1024,64] f32.
// d_out (f32): [loss(1) | z_q_out(4194304) | one_hot(67108864) | indices(65536)]
// train_indices match numpy fp32 argmin BIT-EXACTLY (absmax 0.0, r3/r7/r9/r11).
// FROZEN: per-code serial-FMA chain, pairwise A, contract-off epilogue,
// ascending first-index ties. r11 lesson: unroll-4 regressed (271 vs 238 us) ->
// bottleneck is the per-code codebook LOAD path, not FMA ILP. This round:
//  (a) argmin: revert to unroll-2 chain; stage the 128-row codebook chunk in
//      LDS (32 KB, coalesced float4 copy = bit-exact source change only);
//      inner loop reads via broadcast ds_read_b128 (uniform addr, no conflicts,
//      no L2 port contention). Target VALU-bound (~55 us FMA floor).
//  (b) zq_loss: 4096 blocks (2x oversubscription) to hide fidx->emb gather.
//  (c) onehot_combine byte-identical (will top profile -> diagnose next).

#define K_CODES 1024
#define DIM 64
#define NPTS 65536            // 16*64*64 points
#define RANGES 8
#define CPR 128               // codes per range
#define ZQ_OFF 1
#define OH_OFF (1 + 4194304)
#define IDX_OFF (1 + 4194304 + 67108864)

// numpy pairwise_sum of x[c]*x[c], n=64: classic 8-accumulator pattern.
__device__ __forceinline__ float np_sumsq64(const float* x) {
#pragma clang fp contract(off)
    float t[DIM];
#pragma unroll
    for (int c = 0; c < DIM; ++c) t[c] = x[c] * x[c];
    float r[8];
#pragma unroll
    for (int j = 0; j < 8; ++j) r[j] = t[j];
#pragma unroll
    for (int i = 8; i < DIM; i += 8)
#pragma unroll
        for (int j = 0; j < 8; ++j) r[j] += t[i + j];
    return ((r[0] + r[1]) + (r[2] + r[3])) + ((r[4] + r[5]) + (r[6] + r[7]));
}

__global__ __launch_bounds__(256) void bk_kernel(const float* __restrict__ emb,
                                                 float* __restrict__ bkf) {
    int k = blockIdx.x * 256 + threadIdx.x;
    if (k >= K_CODES) return;
    bkf[k] = np_sumsq64(emb + (size_t)k * DIM);
}

// Each block: 256 points x 128 codes (one k-range). LDS-staged codebook chunk;
// per-code math and compare order identical to the proven 238-us r3 kernel.
__global__ __launch_bounds__(256) void argmin_partial(
    const float* __restrict__ z, const float* __restrict__ emb,
    const float* __restrict__ bkf,
    float* __restrict__ pscore, int* __restrict__ pidx) {
    __shared__ float se[CPR][DIM];      // 32 KB
    int t = threadIdx.x;
    int ptblk = blockIdx.x & 255;
    int range = blockIdx.x >> 8;
    int kbase = range * CPR;

    // stage codebook chunk: pure bit-copy (coalesced float4)
    {
        const float4* src = (const float4*)(emb + (size_t)kbase * DIM);
        float4* dst = (float4*)(&se[0][0]);
#pragma unroll
        for (int i = 0; i < 8; ++i)     // 128*64/4 = 2048 float4 / 256 thr
            dst[t + i * 256] = src[t + i * 256];
    }
    __syncthreads();

    int n = ptblk * 256 + t;
    int b = n >> 12, hw = n & 4095;
    const float* zb = z + ((size_t)b << 18) + hw;   // b*64*4096 + hw
    float zd[DIM];
#pragma unroll
    for (int c = 0; c < DIM; ++c) zd[c] = zb[(size_t)c << 12];

    float A = np_sumsq64(zd);

    float best = FLT_MAX;
    int bi = kbase;
#pragma unroll 2
    for (int k = 0; k < CPR; ++k) {
        const float4* e4 = (const float4*)(&se[k][0]);   // broadcast ds_read
        float m = 0.0f;
#pragma unroll
        for (int i = 0; i < 16; ++i) {
            float4 v = e4[i];
            m = __builtin_fmaf(zd[i * 4 + 0], v.x, m);
            m = __builtin_fmaf(zd[i * 4 + 1], v.y, m);
            m = __builtin_fmaf(zd[i * 4 + 2], v.z, m);
            m = __builtin_fmaf(zd[i * 4 + 3], v.w, m);
        }
        float d;
        {
#pragma clang fp contract(off)
            float t1 = A + bkf[kbase + k];
            d = t1 - 2.0f * m;
        }
        if (d < best) { best = d; bi = kbase + k; }   // strict <: first index wins
    }
    pscore[range * NPTS + n] = best;
    pidx[range * NPTS + n] = bi;
}

// Fused: per block of 64 points -- 8-range combine (first-index ties), write
// fidx + float idx, zero-fill the block's contiguous 64-row one-hot slab
// (256 KB) with aligned float4, then scatter the 64 ones. (unchanged from r11)
__global__ __launch_bounds__(256) void onehot_combine(
    const float* __restrict__ pscore, const int* __restrict__ pidx,
    int* __restrict__ fidx, float* __restrict__ out) {
    __shared__ int sbi[64];
    int t = threadIdx.x;
    int n0 = blockIdx.x * 64;

    if (t < 64) {
        int n = n0 + t;
        float best = pscore[n];
        int bi = pidx[n];
#pragma unroll
        for (int r = 1; r < RANGES; ++r) {
            float s = pscore[r * NPTS + n];
            if (s < best) { best = s; bi = pidx[r * NPTS + n]; }  // ascending
        }
        fidx[n] = bi;
        out[IDX_OFF + n] = (float)bi;
        sbi[t] = bi;
    }
    __syncthreads();

    // zero-fill: dwords [base, base+65536); base%4==1 -> head 3, 16383 quads, tail 1
    size_t base = (size_t)OH_OFF + (size_t)n0 * K_CODES;
    float4* qb = (float4*)(out + base + 3);
    const float4 z4 = make_float4(0.f, 0.f, 0.f, 0.f);
#pragma unroll
    for (int i = 0; i < 64; ++i) {
        int q = i * 256 + t;
        if (q < 16383) qb[q] = z4;
    }
    if (t == 0) {
        out[base] = 0.f; out[base + 1] = 0.f; out[base + 2] = 0.f;
        out[base + 65535] = 0.f;
    }
    __syncthreads();
    if (t < 64) out[base + (size_t)t * K_CODES + sbi[t]] = 1.0f;
}

// Grid-stride over aligned quads of the z_q output region; block-level partial
// loss reduction, one atomicAdd per block. Grid 4096 for gather-latency hiding.
#define ZQ_QUADS 1048575      // (4194304 - 3 - 1) / 4
__global__ __launch_bounds__(256) void zq_loss_kernel(
    const float* __restrict__ z, const float* __restrict__ emb,
    const int* __restrict__ fidx, float* __restrict__ out) {
    int tid = blockIdx.x * 256 + threadIdx.x;
    int stride = gridDim.x * 256;
    float acc = 0.0f;
    for (int q = tid; q < ZQ_QUADS; q += stride) {
        int o = 3 + 4 * q;
        float4 r;
        float* rp = (float*)&r;
#pragma unroll
        for (int j = 0; j < 4; ++j) {
            int oj = o + j;
            int hw = oj & 4095;
            int c = (oj >> 12) & 63;
            int b = oj >> 18;
            int n = (b << 12) | hw;
            float zq = emb[(size_t)fidx[n] * DIM + c];
            float zp = z[oj];
            rp[j] = zp + (zq - zp);
            float d = zq - zp;
            acc = __builtin_fmaf(d, d, acc);
        }
        *(float4*)(out + ZQ_OFF + o) = r;
    }
    if (tid == 0) {
        int extras[4] = {0, 1, 2, 4194303};
#pragma unroll
        for (int e = 0; e < 4; ++e) {
            int oj = extras[e];
            int hw = oj & 4095;
            int c = (oj >> 12) & 63;
            int b = oj >> 18;
            int n = (b << 12) | hw;
            float zq = emb[(size_t)fidx[n] * DIM + c];
            float zp = z[oj];
            out[ZQ_OFF + oj] = zp + (zq - zp);
            float d = zq - zp;
            acc = __builtin_fmaf(d, d, acc);
        }
    }
#pragma unroll
    for (int off = 32; off; off >>= 1) acc += __shfl_down(acc, off, 64);
    __shared__ float wsum[4];
    if ((threadIdx.x & 63) == 0) wsum[threadIdx.x >> 6] = acc;
    __syncthreads();
    if (threadIdx.x == 0) {
        float s = (wsum[0] + wsum[1]) + (wsum[2] + wsum[3]);
        // loss = (1 + beta) * mean((z_q - z)^2), beta = 0.25, N = 4194304
        atomicAdd(out, s * (1.25f / 4194304.0f));
    }
}

extern "C" void kernel_launch(void* const* d_in, const int* in_sizes, int n_in,
                              void* d_out, int out_size, void* d_ws, size_t ws_size,
                              hipStream_t stream) {
    const float* z = (const float*)d_in[0];
    const float* emb = (const float*)d_in[1];
    float* out = (float*)d_out;
    char* ws = (char*)d_ws;
    float* bkf = (float*)ws;                                     // 4 KB
    float* pscore = (float*)(ws + 8192);                         // 2 MB
    int* pidx = (int*)(ws + 8192 + (size_t)RANGES * NPTS * 4);   // 2 MB
    int* fidx = (int*)(ws + 8192 + (size_t)RANGES * NPTS * 8);   // 256 KB

    hipMemsetAsync(d_out, 0, 4, stream);   // loss accumulator
    hipLaunchKernelGGL(bk_kernel, dim3(4), dim3(256), 0, stream, emb, bkf);
    hipLaunchKernelGGL(argmin_partial, dim3(256 * RANGES), dim3(256), 0, stream,
                       z, emb, bkf, pscore, pidx);
    hipLaunchKernelGGL(onehot_combine, dim3(NPTS / 64), dim3(256), 0, stream,
                       pscore, pidx, fidx, out);
    hipLaunchKernelGGL(zq_loss_kernel, dim3(4096), dim3(256), 0, stream,
                       z, emb, fidx, out);
}